// Round 8
// baseline (729.238 us; speedup 1.0000x reference)
//
#include <hip/hip_runtime.h>
#include <math.h>

typedef _Float16 half_t;
typedef _Float16 half8_t __attribute__((ext_vector_type(8)));
typedef float float4_t __attribute__((ext_vector_type(4)));

#define T_ 64
#define B_ 256
#define D_ 16
#define S_ 64
#define H_ 128
#define O_ 8
#define NSTEP 63
#define NT 1024

// ws layout (halves): Wf3 [1024][128] | Wf1 [128][64] | Wf2 [128][128], row-major fp16
#define W3_OFF 0
#define W1_OFF 131072
#define W2_OFF 139264
#define WS_HALVES 155648

#define MFMA16(a, b, c) __builtin_amdgcn_mfma_f32_16x16x32_f16(a, b, c, 0, 0, 0)

// AE[j] = coefficients on k[0..j] producing the NEXT stage input (j<5) or B_SOL (j==5)
__device__ constexpr float AE[6][6] = {
  {0.161f, 0.f, 0.f, 0.f, 0.f, 0.f},
  {-0.008480655492356989f, 0.335480655492357f, 0.f, 0.f, 0.f, 0.f},
  {2.8971530571054935f, -6.359448489975075f, 4.3622954328695815f, 0.f, 0.f, 0.f},
  {5.325864828439257f, -11.748883564062828f, 7.4955393428898365f, -0.09249506636175525f, 0.f, 0.f},
  {5.86145544294642f, -12.92096931784711f, 8.159367898576159f, -0.071584973281401f, -0.028269050394068383f, 0.f},
  {0.09646076681806523f, 0.01f, 0.4798896504144996f, 1.379008574103742f, -3.290069515436081f, 2.324710524099774f}
};
__device__ constexpr float CCn[6] = {0.f, 0.161f, 0.327f, 0.9f, 0.9800255409045097f, 1.f};

__device__ __forceinline__ float softplus_f(float x) {
  return fmaxf(x, 0.f) + __logf(1.f + __expf(-fabsf(x)));
}
__device__ __forceinline__ float tanh_f(float x) {
  float xc = fminf(fmaxf(x, -12.f), 12.f);
  float e = __expf(2.f * xc);
  return (e - 1.f) * __builtin_amdgcn_rcpf(e + 1.f);
}

// ---------------- prologue: fp32 -> fp16 weight conversion (row-major) ----------------
__global__ __launch_bounds__(256) void convert_kernel(
    const float* __restrict__ Wf1, const float* __restrict__ Wf2,
    const float* __restrict__ Wf3, half_t* __restrict__ wsh)
{
  int q = blockIdx.x * 256 + threadIdx.x;
  if (q < W1_OFF) wsh[q] = (half_t)Wf3[q];
  else if (q < W2_OFF) wsh[q] = (half_t)Wf1[q - W1_OFF];
  else if (q < WS_HALVES) wsh[q] = (half_t)Wf2[q - W2_OFF];
}

// ---------------- main kernel: 16 waves (4/SIMD), MFMA, AGPR-resident B ----------------
// Work split per stage:
//   h1 (waves 0-7):  tile n=16w+c of Wf1 (K=64, 2 MFMA), softplus on q==0
//   h2 (waves 8-15): tile n=16(w-8)+c of Wf2 (K=128, 4 MFMA); wave 15 also does
//                    the out-projection during the h1 phase (it's idle there)
//   G3 (all):        tiles s=4w..4w+3 of Wf3 (16 MFMA); quad q owns s=4w+q:
//                    1 tanh, 3-cndmask select, 4 shfl reduce; c==0 lane is the
//                    RK leader for that s (64 leaders == 64 s values).
// A-operand is the activation vector row-replicated (verified R7 layout).
__global__ void __launch_bounds__(NT) __attribute__((amdgpu_waves_per_eu(4, 4)))
cde_kernel_mfma(
    const float* __restrict__ ts,
    const float* __restrict__ coeff_d,
    const float* __restrict__ coeff_c,
    const float* __restrict__ coeff_b,
    const float* __restrict__ coeff_a,
    const float* __restrict__ Wi1, const float* __restrict__ bi1,
    const float* __restrict__ Wi2, const float* __restrict__ bi2,
    const float* __restrict__ bf1, const float* __restrict__ bf2,
    const float* __restrict__ bf3,
    const float* __restrict__ Wr, const float* __restrict__ br,
    const half_t* __restrict__ wsh,
    float* __restrict__ out)
{
  __shared__ __align__(16) half_t syj_h[S_];
  __shared__ __align__(16) half_t sh1h[H_];
  __shared__ __align__(16) half_t sh2h[H_];
  __shared__ float syf[S_];
  __shared__ float sWr[O_ * S_];
  __shared__ float sbr[O_];
  __shared__ float sx0[D_];
  __shared__ float sini[H_];
  __shared__ float shs[T_];

  const int tid = threadIdx.x;
  const int b = blockIdx.x;
  const int w = tid >> 6;          // wave 0..15
  const int lane = tid & 63;
  const int q = lane >> 4;         // quad 0..3
  const int c = lane & 15;         // fragment column

  const half_t* __restrict__ w3p = wsh + W3_OFF;
  const half_t* __restrict__ w1p = wsh + W1_OFF;
  const half_t* __restrict__ w2p = wsh + W2_OFF;

  // ---- persistent B fragments (AGPR-resident; MFMA reads them natively) ----
  const bool isH1 = (w < 8);
  const int nO = 16 * (isH1 ? w : (w - 8)) + c;   // output column for h1 or h2 tile
  half8_t bWa[4];                                 // Wf1 (2 used) or Wf2 (4 used)
  if (isH1) {
    #pragma unroll
    for (int ks = 0; ks < 2; ++ks)
      bWa[ks] = *(const half8_t*)(w1p + nO * S_ + ks * 32 + q * 8);
    bWa[2] = bWa[0]; bWa[3] = bWa[1];
  } else {
    #pragma unroll
    for (int ks = 0; ks < 4; ++ks)
      bWa[ks] = *(const half8_t*)(w2p + nO * H_ + ks * 32 + q * 8);
  }
  const float biasO = isH1 ? bf1[nO] : bf2[nO];

  half8_t bW3[4][4];               // tiles s=4w+tt, rows r=16s+c
  #pragma unroll
  for (int tt = 0; tt < 4; ++tt) {
    const int r = 16 * (4 * w + tt) + c;
    #pragma unroll
    for (int ks = 0; ks < 4; ++ks)
      bW3[tt][ks] = *(const half8_t*)(w3p + (size_t)r * H_ + ks * 32 + q * 8);
  }
  const int sE = 4 * w + q;                    // the s this quad owns
  const float bf3E = bf3[16 * sE + c];
  const bool isLeader = (c == 0);

  // ---- one-time staging + y0 ----
  if (tid < O_ * S_) sWr[tid] = Wr[tid];
  if (tid < O_) sbr[tid] = br[tid];
  if (tid < D_) sx0[tid] = coeff_a[(size_t)b * NSTEP * D_ + tid];
  if (tid < NSTEP) shs[tid] = ts[tid + 1] - ts[tid];
  __syncthreads();
  if (tid < H_) {
    float acc = bi1[tid];
    #pragma unroll
    for (int d = 0; d < D_; ++d) acc += sx0[d] * Wi1[tid * D_ + d];
    sini[tid] = softplus_f(acc);
  }
  __syncthreads();
  if (tid < S_) {
    float acc = bi2[tid];
    for (int h = 0; h < H_; ++h) acc += sini[h] * Wi2[tid * H_ + h];
    syf[tid] = acc;
  }
  __syncthreads();

  float yr = 0.f;
  float kr[6] = {0.f, 0.f, 0.f, 0.f, 0.f, 0.f};
  if (isLeader) {
    yr = syf[sE];
    syj_h[sE] = (half_t)yr;
  }
  __syncthreads();

  const float4_t Zv = {0.f, 0.f, 0.f, 0.f};

  // ---- time loop ----
  for (int t = 0; t < NSTEP; ++t) {
    const float hstep = shs[t];
    const size_t cidx = ((size_t)b * NSTEP + t) * D_ + c;
    const float cbv = coeff_b[cidx];
    const float ccv = coeff_c[cidx];
    const float cdv = coeff_d[cidx];

    #pragma unroll
    for (int j = 0; j < 6; ++j) {
      // ---- phase 1: h1 (waves 0-7); projection on wave 15 at j==0 ----
      if (isH1) {
        const half8_t* ap = (const half8_t*)syj_h;
        half8_t a0 = ap[q];           // k = q*8 ..
        half8_t a1 = ap[4 + q];       // k = 32 + q*8 ..
        float4_t acc = MFMA16(a0, bWa[0], Zv);
        acc = MFMA16(a1, bWa[1], acc);
        if (q == 0) sh1h[nO] = (half_t)softplus_f(acc[0] + biasO);
      } else if (w == 15 && j == 0) {
        const int oo = lane >> 3, kc = lane & 7;
        float a = 0.f;
        #pragma unroll
        for (int i = 0; i < 8; ++i) a += syf[kc * 8 + i] * sWr[oo * S_ + kc * 8 + i];
        a += __shfl_down(a, 4, 8);
        a += __shfl_down(a, 2, 8);
        a += __shfl_down(a, 1, 8);
        if (kc == 0) out[((size_t)b * T_ + t) * O_ + oo] = a + sbr[oo];
      }
      __syncthreads();   // B1

      // ---- phase 2: h2 (waves 8-15) ----
      if (!isH1) {
        const half8_t* ap = (const half8_t*)sh1h;
        half8_t a0 = ap[q], a1 = ap[4 + q], a2 = ap[8 + q], a3 = ap[12 + q];
        float4_t acc = MFMA16(a0, bWa[0], Zv);
        acc = MFMA16(a1, bWa[1], acc);
        acc = MFMA16(a2, bWa[2], acc);
        acc = MFMA16(a3, bWa[3], acc);
        if (q == 0) sh2h[nO] = (half_t)softplus_f(acc[0] + biasO);
      }
      __syncthreads();   // B2

      // ---- phase 3: GEMV3 (all waves) + epilogue + RK update ----
      {
        const half8_t* ap = (const half8_t*)sh2h;
        half8_t a0 = ap[q], a1 = ap[4 + q], a2 = ap[8 + q], a3 = ap[12 + q];
        float4_t acc3[4];
        #pragma unroll
        for (int tt = 0; tt < 4; ++tt) acc3[tt] = MFMA16(a0, bW3[tt][0], Zv);
        #pragma unroll
        for (int tt = 0; tt < 4; ++tt) acc3[tt] = MFMA16(a1, bW3[tt][1], acc3[tt]);
        #pragma unroll
        for (int tt = 0; tt < 4; ++tt) acc3[tt] = MFMA16(a2, bW3[tt][2], acc3[tt]);
        #pragma unroll
        for (int tt = 0; tt < 4; ++tt) acc3[tt] = MFMA16(a3, bW3[tt][3], acc3[tt]);

        // quad q keeps tile q (every lane's reg0 is valid for col c)
        const float s01 = (q & 1) ? acc3[1][0] : acc3[0][0];
        const float s23 = (q & 1) ? acc3[3][0] : acc3[2][0];
        const float v = (q & 2) ? s23 : s01;

        const float frac = CCn[j] * hstep;
        const float dx = cbv + frac * (2.f * ccv + 3.f * frac * cdv);
        float p = tanh_f(v + bf3E) * dx;
        // reduce over the 16 cols (=d) within the quad
        p += __shfl_xor(p, 1);
        p += __shfl_xor(p, 2);
        p += __shfl_xor(p, 4);
        p += __shfl_xor(p, 8);

        if (isLeader) {
          kr[j] = p;
          float sa = AE[j][0] * kr[0];
          #pragma unroll
          for (int m = 1; m < 6; ++m) if (m <= j) sa += AE[j][m] * kr[m];
          float yn = yr + hstep * sa;
          if (j == 5) { yr = yn; syf[sE] = yn; }
          syj_h[sE] = (half_t)yn;
        }
      }
      __syncthreads();   // B3
    }
  }

  // final projection: out[b,63,:]
  if (w == 15) {
    const int oo = lane >> 3, kc = lane & 7;
    float a = 0.f;
    #pragma unroll
    for (int i = 0; i < 8; ++i) a += syf[kc * 8 + i] * sWr[oo * S_ + kc * 8 + i];
    a += __shfl_down(a, 4, 8);
    a += __shfl_down(a, 2, 8);
    a += __shfl_down(a, 1, 8);
    if (kc == 0) out[((size_t)b * T_ + (T_ - 1)) * O_ + oo] = a + sbr[oo];
  }
}

extern "C" void kernel_launch(void* const* d_in, const int* in_sizes, int n_in,
                              void* d_out, int out_size, void* d_ws, size_t ws_size,
                              hipStream_t stream) {
  const float* ts  = (const float*)d_in[0];
  const float* cd  = (const float*)d_in[1];
  const float* cc  = (const float*)d_in[2];
  const float* cb  = (const float*)d_in[3];
  const float* ca  = (const float*)d_in[4];
  const float* Wi1 = (const float*)d_in[5];
  const float* bi1 = (const float*)d_in[6];
  const float* Wi2 = (const float*)d_in[7];
  const float* bi2 = (const float*)d_in[8];
  const float* Wf1 = (const float*)d_in[9];
  const float* bf1 = (const float*)d_in[10];
  const float* Wf2 = (const float*)d_in[11];
  const float* bf2 = (const float*)d_in[12];
  const float* Wf3 = (const float*)d_in[13];
  const float* bf3 = (const float*)d_in[14];
  const float* Wr  = (const float*)d_in[15];
  const float* br  = (const float*)d_in[16];

  half_t* wsh = (half_t*)d_ws;
  hipLaunchKernelGGL(convert_kernel, dim3((WS_HALVES + 255) / 256), dim3(256), 0, stream,
                     Wf1, Wf2, Wf3, wsh);
  hipLaunchKernelGGL(cde_kernel_mfma, dim3(B_), dim3(NT), 0, stream,
                     ts, cd, cc, cb, ca, Wi1, bi1, Wi2, bi2,
                     bf1, bf2, bf3, Wr, br, wsh, (float*)d_out);
}

// Round 9
// 632.904 us; speedup vs baseline: 1.1522x; 1.1522x over previous
//
#include <hip/hip_runtime.h>
#include <math.h>

typedef _Float16 half_t;
typedef _Float16 half8_t __attribute__((ext_vector_type(8)));
typedef float float4_t __attribute__((ext_vector_type(4)));

#define T_ 64
#define B_ 256
#define D_ 16
#define S_ 64
#define H_ 128
#define O_ 8
#define NSTEP 63
#define NT 1024

// ws layout (halves):
//   [0, 131072)        Wf3 row-major [1024][128]
//   [131072, 139264)   Wf1 fragment-major: [g<8][n<128][i<8], k = (g>>2)*32 + (g&3)*8 + i
//   [139264, 155648)   Wf2 fragment-major: [g<16][n<128][i<8], same k map
#define W3_OFF 0
#define W1_OFF 131072
#define W2_OFF 139264
#define WS_HALVES 155648

#define MFMA16(a, b, c) __builtin_amdgcn_mfma_f32_16x16x32_f16(a, b, c, 0, 0, 0)

// AE[j] = coefficients on k[0..j] producing the NEXT stage input (j<5) or B_SOL (j==5)
__device__ constexpr float AE[6][6] = {
  {0.161f, 0.f, 0.f, 0.f, 0.f, 0.f},
  {-0.008480655492356989f, 0.335480655492357f, 0.f, 0.f, 0.f, 0.f},
  {2.8971530571054935f, -6.359448489975075f, 4.3622954328695815f, 0.f, 0.f, 0.f},
  {5.325864828439257f, -11.748883564062828f, 7.4955393428898365f, -0.09249506636175525f, 0.f, 0.f},
  {5.86145544294642f, -12.92096931784711f, 8.159367898576159f, -0.071584973281401f, -0.028269050394068383f, 0.f},
  {0.09646076681806523f, 0.01f, 0.4798896504144996f, 1.379008574103742f, -3.290069515436081f, 2.324710524099774f}
};
__device__ constexpr float CCn[6] = {0.f, 0.161f, 0.327f, 0.9f, 0.9800255409045097f, 1.f};

__device__ __forceinline__ float softplus_f(float x) {
  return fmaxf(x, 0.f) + __logf(1.f + __expf(-fabsf(x)));
}
__device__ __forceinline__ float tanh_f(float x) {
  float xc = fminf(fmaxf(x, -12.f), 12.f);
  float e = __expf(2.f * xc);
  return (e - 1.f) * __builtin_amdgcn_rcpf(e + 1.f);
}

// ---------------- prologue: fp32 -> fp16 weight conversion ----------------
__global__ __launch_bounds__(256) void convert_kernel(
    const float* __restrict__ Wf1, const float* __restrict__ Wf2,
    const float* __restrict__ Wf3, half_t* __restrict__ wsh)
{
  int qi = blockIdx.x * 256 + threadIdx.x;
  if (qi < W1_OFF) {
    wsh[qi] = (half_t)Wf3[qi];
  } else if (qi < W2_OFF) {
    int rem = qi - W1_OFF;                 // [0, 8192)
    int g = rem >> 10, n = (rem >> 3) & 127, i = rem & 7;
    int k = (g >> 2) * 32 + (g & 3) * 8 + i;
    wsh[qi] = (half_t)Wf1[n * S_ + k];
  } else if (qi < WS_HALVES) {
    int rem = qi - W2_OFF;                 // [0, 16384)
    int g = rem >> 10, n = (rem >> 3) & 127, i = rem & 7;
    int k = (g >> 2) * 32 + (g & 3) * 8 + i;
    wsh[qi] = (half_t)Wf2[n * H_ + k];
  }
}

// ---------------- main kernel: 16 waves (4/SIMD), Wf3-only persistent ----------------
// h1 (waves 0-7):  tile n=16w+c of Wf1, fragments re-read from LDS each stage
// h2 (waves 8-15): tile n=16(w-8)+c of Wf2, fragments re-read (issued in h1 phase)
// G3 (all):        tiles s=4w+tt (tt<4) of Wf3, persistent AGPR fragments (64 regs)
// Anti-LICM: asm "+v" on the LDS offset so the per-stage fragment loads are
// never hoisted into persistent registers (would exceed the 128-reg cap -> scratch).
__global__ void __launch_bounds__(NT) __attribute__((amdgpu_waves_per_eu(4, 4)))
cde_kernel_mfma(
    const float* __restrict__ ts,
    const float* __restrict__ coeff_d,
    const float* __restrict__ coeff_c,
    const float* __restrict__ coeff_b,
    const float* __restrict__ coeff_a,
    const float* __restrict__ Wi1, const float* __restrict__ bi1,
    const float* __restrict__ Wi2, const float* __restrict__ bi2,
    const float* __restrict__ bf1, const float* __restrict__ bf2,
    const float* __restrict__ bf3,
    const float* __restrict__ Wr, const float* __restrict__ br,
    const half_t* __restrict__ wsh,
    float* __restrict__ out)
{
  __shared__ __align__(16) half_t sW1L[8192];    // 16 KB, fragment-major
  __shared__ __align__(16) half_t sW2L[16384];   // 32 KB, fragment-major
  __shared__ __align__(16) half_t syj_h[S_];
  __shared__ __align__(16) half_t sh1h[H_];
  __shared__ __align__(16) half_t sh2h[H_];
  __shared__ float syf[S_];
  __shared__ float skr[6][S_];
  __shared__ float sbf1[H_], sbf2[H_];
  __shared__ float sWr[O_ * S_];
  __shared__ float sbr[O_];
  __shared__ float sx0[D_];
  __shared__ float sini[H_];
  __shared__ float shs[T_];

  const int tid = threadIdx.x;
  const int b = blockIdx.x;
  const int w = tid >> 6;          // wave 0..15
  const int lane = tid & 63;
  const int q = lane >> 4;         // quad 0..3
  const int c = lane & 15;         // fragment column

  const bool isH1 = (w < 8);
  const int nO = 16 * (isH1 ? w : (w - 8)) + c;

  // ---- persistent Wf3 fragments (exactly 64 regs, AGPR-resident) ----
  half8_t bW3[4][4];
  #pragma unroll
  for (int tt = 0; tt < 4; ++tt) {
    const int r = 16 * (4 * w + tt) + c;
    #pragma unroll
    for (int ks = 0; ks < 4; ++ks)
      bW3[tt][ks] = *(const half8_t*)(wsh + W3_OFF + (size_t)r * H_ + ks * 32 + q * 8);
  }
  const int sE = 4 * w + q;
  const float bf3E = bf3[16 * sE + c];
  const bool isLeader = (c == 0);

  // ---- one-time staging ----
  {
    const float4* s1 = (const float4*)(wsh + W1_OFF);
    float4* d1 = (float4*)sW1L;
    for (int i = tid; i < 1024; i += NT) d1[i] = s1[i];
    const float4* s2 = (const float4*)(wsh + W2_OFF);
    float4* d2 = (float4*)sW2L;
    for (int i = tid; i < 2048; i += NT) d2[i] = s2[i];
  }
  if (tid < O_ * S_) sWr[tid] = Wr[tid];
  if (tid < O_) sbr[tid] = br[tid];
  if (tid < D_) sx0[tid] = coeff_a[(size_t)b * NSTEP * D_ + tid];
  if (tid < NSTEP) shs[tid] = ts[tid + 1] - ts[tid];
  if (tid < H_) { sbf1[tid] = bf1[tid]; sbf2[tid] = bf2[tid]; }
  __syncthreads();

  // ---- y0 = softplus(x0 @ Wi1^T + bi1) @ Wi2^T + bi2 (fp32, once) ----
  if (tid < H_) {
    float acc = bi1[tid];
    #pragma unroll
    for (int d = 0; d < D_; ++d) acc += sx0[d] * Wi1[tid * D_ + d];
    sini[tid] = softplus_f(acc);
  }
  __syncthreads();
  if (tid < S_) {
    float acc = bi2[tid];
    for (int h = 0; h < H_; ++h) acc += sini[h] * Wi2[tid * H_ + h];
    syf[tid] = acc;
  }
  __syncthreads();

  float yr = 0.f;
  if (isLeader) {
    yr = syf[sE];
    syj_h[sE] = (half_t)yr;
  }
  __syncthreads();

  const float4_t Zv = {0.f, 0.f, 0.f, 0.f};
  const char* sW1b = (const char*)sW1L;
  const char* sW2b = (const char*)sW2L;

  // ---- time loop ----
  for (int t = 0; t < NSTEP; ++t) {
    const float hstep = shs[t];
    const size_t cidx = ((size_t)b * NSTEP + t) * D_ + c;
    const float cbv = coeff_b[cidx];
    const float ccv = coeff_c[cidx];
    const float cdv = coeff_d[cidx];

    #pragma unroll
    for (int j = 0; j < 6; ++j) {
      half8_t wf0, wf1, wf2, wf3;
      // ---- phase 1: h1 (waves 0-7); h2 waves prefetch W2 frags; wave 15 projects ----
      if (isH1) {
        uint32_t o1 = (uint32_t)((q * 128 + nO) * 16);
        asm volatile("" : "+v"(o1));
        wf0 = *(const half8_t*)(sW1b + o1);
        wf1 = *(const half8_t*)(sW1b + o1 + 8192);
        const half8_t* ap = (const half8_t*)syj_h;
        half8_t a0 = ap[q];
        half8_t a1 = ap[4 + q];
        float4_t acc = MFMA16(a0, wf0, Zv);
        acc = MFMA16(a1, wf1, acc);
        if (q == 0) sh1h[nO] = (half_t)softplus_f(acc[0] + sbf1[nO]);
      } else {
        uint32_t o2 = (uint32_t)((q * 128 + nO) * 16);
        asm volatile("" : "+v"(o2));
        wf0 = *(const half8_t*)(sW2b + o2);
        wf1 = *(const half8_t*)(sW2b + o2 + 8192);
        wf2 = *(const half8_t*)(sW2b + o2 + 16384);
        wf3 = *(const half8_t*)(sW2b + o2 + 24576);
        if (w == 15 && j == 0) {
          const int oo = lane >> 3, kc = lane & 7;
          float a = 0.f;
          #pragma unroll
          for (int i = 0; i < 8; ++i) a += syf[kc * 8 + i] * sWr[oo * S_ + kc * 8 + i];
          a += __shfl_down(a, 4, 8);
          a += __shfl_down(a, 2, 8);
          a += __shfl_down(a, 1, 8);
          if (kc == 0) out[((size_t)b * T_ + t) * O_ + oo] = a + sbr[oo];
        }
      }
      __syncthreads();   // B1

      // ---- phase 2: h2 (waves 8-15) ----
      if (!isH1) {
        const half8_t* ap = (const half8_t*)sh1h;
        half8_t a0 = ap[q], a1 = ap[4 + q], a2 = ap[8 + q], a3 = ap[12 + q];
        float4_t acc = MFMA16(a0, wf0, Zv);
        acc = MFMA16(a1, wf1, acc);
        acc = MFMA16(a2, wf2, acc);
        acc = MFMA16(a3, wf3, acc);
        if (q == 0) sh2h[nO] = (half_t)softplus_f(acc[0] + sbf2[nO]);
      }
      __syncthreads();   // B2

      // ---- phase 3: GEMV3 (all waves) + epilogue + RK update ----
      {
        const half8_t* ap = (const half8_t*)sh2h;
        half8_t a0 = ap[q], a1 = ap[4 + q], a2 = ap[8 + q], a3 = ap[12 + q];
        float4_t acc3[4];
        #pragma unroll
        for (int tt = 0; tt < 4; ++tt) acc3[tt] = MFMA16(a0, bW3[tt][0], Zv);
        #pragma unroll
        for (int tt = 0; tt < 4; ++tt) acc3[tt] = MFMA16(a1, bW3[tt][1], acc3[tt]);
        #pragma unroll
        for (int tt = 0; tt < 4; ++tt) acc3[tt] = MFMA16(a2, bW3[tt][2], acc3[tt]);
        #pragma unroll
        for (int tt = 0; tt < 4; ++tt) acc3[tt] = MFMA16(a3, bW3[tt][3], acc3[tt]);

        const float s01 = (q & 1) ? acc3[1][0] : acc3[0][0];
        const float s23 = (q & 1) ? acc3[3][0] : acc3[2][0];
        const float v = (q & 2) ? s23 : s01;

        const float frac = CCn[j] * hstep;
        const float dx = cbv + frac * (2.f * ccv + 3.f * frac * cdv);
        float p = tanh_f(v + bf3E) * dx;
        p += __shfl_xor(p, 1);
        p += __shfl_xor(p, 2);
        p += __shfl_xor(p, 4);
        p += __shfl_xor(p, 8);

        if (isLeader) {
          float sa = AE[j][j] * p;
          #pragma unroll
          for (int m = 0; m < 5; ++m) if (m < j) sa += AE[j][m] * skr[m][sE];
          if (j < 5) skr[j][sE] = p;
          float yn = yr + hstep * sa;
          if (j == 5) { yr = yn; syf[sE] = yn; }
          syj_h[sE] = (half_t)yn;
        }
      }
      __syncthreads();   // B3
    }
  }

  // final projection: out[b,63,:]
  if (w == 15) {
    const int oo = lane >> 3, kc = lane & 7;
    float a = 0.f;
    #pragma unroll
    for (int i = 0; i < 8; ++i) a += syf[kc * 8 + i] * sWr[oo * S_ + kc * 8 + i];
    a += __shfl_down(a, 4, 8);
    a += __shfl_down(a, 2, 8);
    a += __shfl_down(a, 1, 8);
    if (kc == 0) out[((size_t)b * T_ + (T_ - 1)) * O_ + oo] = a + sbr[oo];
  }
}

extern "C" void kernel_launch(void* const* d_in, const int* in_sizes, int n_in,
                              void* d_out, int out_size, void* d_ws, size_t ws_size,
                              hipStream_t stream) {
  const float* ts  = (const float*)d_in[0];
  const float* cd  = (const float*)d_in[1];
  const float* cc  = (const float*)d_in[2];
  const float* cb  = (const float*)d_in[3];
  const float* ca  = (const float*)d_in[4];
  const float* Wi1 = (const float*)d_in[5];
  const float* bi1 = (const float*)d_in[6];
  const float* Wi2 = (const float*)d_in[7];
  const float* bi2 = (const float*)d_in[8];
  const float* Wf1 = (const float*)d_in[9];
  const float* bf1 = (const float*)d_in[10];
  const float* Wf2 = (const float*)d_in[11];
  const float* bf2 = (const float*)d_in[12];
  const float* Wf3 = (const float*)d_in[13];
  const float* bf3 = (const float*)d_in[14];
  const float* Wr  = (const float*)d_in[15];
  const float* br  = (const float*)d_in[16];

  half_t* wsh = (half_t*)d_ws;
  hipLaunchKernelGGL(convert_kernel, dim3((WS_HALVES + 255) / 256), dim3(256), 0, stream,
                     Wf1, Wf2, Wf3, wsh);
  hipLaunchKernelGGL(cde_kernel_mfma, dim3(B_), dim3(NT), 0, stream,
                     ts, cd, cc, cb, ca, Wi1, bi1, Wi2, bi2,
                     bf1, bf2, bf3, Wr, br, wsh, (float*)d_out);
}